// Round 7
// baseline (355.785 us; speedup 1.0000x reference)
//
#include <hip/hip_runtime.h>
#include <hip/hip_bf16.h>

// ConvAttention: 4x [conv(1,5)+BN+LReLU(0.3)] -> per-(b,c) attention over W with
// softmax over last axis, + pe residual.  B=16 Cin=32 Cout=64 H=16 W=512.
// fp32 in / fp32 out.  Internals bf16 MFMA, fp32 accumulation.
// R7: (a) attn: no launch-bounds VGPR cap (R6's ",4" forced 64 VGPR -> 212 MB
// scratch-spill traffic); K-frags re-read from LDS instead of bk[8] reg cache.
// (b) conv: 512 blocks (b,h,w-half) computing all 4 sel from one x stage ->
// x fetched once (was 4x).  d_out stays write-only, single writer.

typedef __attribute__((ext_vector_type(8))) short short8;   // 8 x bf16 (4 VGPR)
typedef __attribute__((ext_vector_type(4))) float floatx4;  // MFMA acc

#define Q_ELEMS 8388608u     // 16*64*16*512 elements per tensor (q/k/v/pe)
#define LOG2E   1.44269504088896340736f

__device__ __forceinline__ float bf2f(unsigned short u) {
    union { unsigned int i; float f; } c; c.i = ((unsigned int)u) << 16; return c.f;
}
__device__ __forceinline__ unsigned short f2bf(float f) {   // RNE
    union { unsigned int i; float f; } c; c.f = f;
    unsigned int r = c.i + 0x7FFFu + ((c.i >> 16) & 1u);
    return (unsigned short)(r >> 16);
}
__device__ __forceinline__ unsigned int pkbf(float lo, float hi) {  // bf16(hi)<<16|bf16(lo)
    __hip_bfloat162 h2 = __float22bfloat162_rn(make_float2(lo, hi));
    union { __hip_bfloat162 h; unsigned int u; } c; c.h = h2; return c.u;
}

struct AllIn { const void* p[21]; };

// ---------------------------------------------------------------------------
// Conv kernel: one block per (b, h, w-half). Stages x[b,:,h,w-half+halo] ONCE,
// then runs all 4 sel GEMMs from it (x fetch /4 vs per-sel blocks).
// im2col GEMM, M=co(64) N=w(256) K=160, K-order k = t*32+ci.
// Epilogue via per-wave LDS tile -> coalesced uint4 bf16 stores to ws.
// sel==0 (q) output pre-scaled by log2(e) (LReLU commutes with positive scale).
// ---------------------------------------------------------------------------
__global__ __launch_bounds__(256) void conv_kernel(AllIn in,
                                                   unsigned short* __restrict__ ws_out)
{
    __shared__ unsigned short xt[260][40];    // xt[wl][ci]; wl = w - w0g + 2; 20.8 KB
    __shared__ unsigned short Dt[4][16][40];  // per-wave C tile, 5.1 KB   (25.9 total)

    const bool isbf = (*(const unsigned int*)in.p[5] == 0x3F803F80u);

    const int tid = threadIdx.x;
    const int blk = blockIdx.x;               // 512 = 16b * 16h * 2wh
    const int wh = blk & 1, h = (blk >> 1) & 15, b = blk >> 5;
    const int w0g = wh * 256;

    // ---- stage x[b,:,h, w0g-2 .. w0g+257] into LDS (transposed, bf16) ----
    {
        const int wl4 = (tid & 63) * 4;       // w-local 0..252, 4-wide
        const int cg  = tid >> 6;             // ci group 0..3
        for (int it = 0; it < 8; ++it) {
            const int ci = it * 4 + cg;
            const size_t row = ((size_t)(b * 32 + ci) * 16 + h) << 9;
            unsigned short e[4];
            if (isbf) {
                const unsigned short* xp = (const unsigned short*)in.p[0] + row + w0g + wl4;
                #pragma unroll
                for (int j = 0; j < 4; ++j) e[j] = xp[j];
            } else {
                const float4 f = *(const float4*)((const float*)in.p[0] + row + w0g + wl4);
                e[0] = f2bf(f.x); e[1] = f2bf(f.y); e[2] = f2bf(f.z); e[3] = f2bf(f.w);
            }
            #pragma unroll
            for (int j = 0; j < 4; ++j) xt[wl4 + 2 + j][ci] = e[j];
        }
    }
    if (tid < 128) {                          // halo rows 0,1 (w0g-2,-1), 258,259 (+256,+257)
        const int ci = tid >> 2, p = tid & 3;
        const int r  = (p < 2) ? p : 256 + p;
        const int gw = w0g + r - 2;
        unsigned short val = 0;
        if (gw >= 0 && gw < 512) {
            const size_t row = ((size_t)(b * 32 + ci) * 16 + h) << 9;
            val = isbf ? ((const unsigned short*)in.p[0])[row + gw]
                       : f2bf(((const float*)in.p[0])[row + gw]);
        }
        xt[r][ci] = val;
    }
    __syncthreads();

    const int lane = tid & 63, wv = tid >> 6;
    const int n = lane & 15, quad = lane >> 4;
    const int co0 = wv * 16;                  // wave's M-tile

    for (int sel = 0; sel < 4; ++sel) {
        // ---- A frags (weights) straight from global (L2-hot): k = kk*32+quad*8+j ----
        short8 afrag[5];
        {
            const void* wp = in.p[1 + 5 * sel];
            #pragma unroll
            for (int kk = 0; kk < 5; ++kk) {
                short8 a;
                #pragma unroll
                for (int j = 0; j < 8; ++j) {
                    const int idx = (co0 + n) * 160 + (quad * 8 + j) * 5 + kk;
                    a[j] = (short)(isbf ? ((const unsigned short*)wp)[idx]
                                        : f2bf(((const float*)wp)[idx]));
                }
                afrag[kk] = a;
            }
        }
        // ---- BN constants (D rows = quad*4+r); q gets the log2e fold ----
        float sc[4], sh[4];
        #pragma unroll
        for (int r = 0; r < 4; ++r) {
            const int co = co0 + quad * 4 + r;
            const void* gp = in.p[2 + 5 * sel];
            const void* bp = in.p[3 + 5 * sel];
            const void* mp = in.p[4 + 5 * sel];
            const void* vp = in.p[5 + 5 * sel];
            float gg = isbf ? bf2f(((const unsigned short*)gp)[co]) : ((const float*)gp)[co];
            float bb = isbf ? bf2f(((const unsigned short*)bp)[co]) : ((const float*)bp)[co];
            float mm = isbf ? bf2f(((const unsigned short*)mp)[co]) : ((const float*)mp)[co];
            float vv = isbf ? bf2f(((const unsigned short*)vp)[co]) : ((const float*)vp)[co];
            sc[r] = gg * rsqrtf(vv + 1e-5f);
            sh[r] = bb - mm * sc[r];
            if (sel == 0) { sc[r] *= LOG2E; sh[r] *= LOG2E; }
        }

        unsigned short* outq = ws_out + (size_t)sel * Q_ELEMS;
        for (int g = 0; g < 8; ++g) {         // 32-w groups within this half
            const int w0l = g * 32;
            #pragma unroll
            for (int half = 0; half < 2; ++half) {
                const int w0 = w0l + half * 16;
                floatx4 acc = {0.f, 0.f, 0.f, 0.f};
                #pragma unroll
                for (int kk = 0; kk < 5; ++kk) {
                    // input w = (w0g + w0 + n) + kk - 2  -> xt row w0+n+kk
                    short8 bfrag = *(const short8*)&xt[w0 + n + kk][quad * 8];
                    acc = __builtin_amdgcn_mfma_f32_16x16x32_bf16(afrag[kk], bfrag, acc, 0, 0, 0);
                }
                #pragma unroll
                for (int r = 0; r < 4; ++r) {
                    float y = acc[r] * sc[r] + sh[r];
                    y = fmaxf(y, 0.3f * y);                   // LeakyReLU(0.3)
                    Dt[wv][quad * 4 + r][half * 16 + n] = f2bf(y);
                }
            }
            // per-wave roundtrip -> coalesced bf16 uint4 stores
            __asm__ volatile("" ::: "memory");
            const uint4 d = *(const uint4*)&Dt[wv][n][quad * 8];
            __asm__ volatile("" ::: "memory");
            *(uint4*)&outq[(((size_t)(b * 64 + co0 + n) * 16 + h) << 9)
                           + w0g + w0l + quad * 8] = d;
        }
    }
}

// ---------------------------------------------------------------------------
// Attention kernel: one block (4 waves) per (b,c) pair.
//   pass A: l[w] = sum_v exp2(S'[w,v]); S' = Q'^T K (q pre-scaled by log2e)
//   pass B: out[h,v] = sum_w (V[h,w]/l[w]) * exp2(S'[w,v])  + pe[h,v]
// No VGPR cap (R6 lesson: cap => scratch spill => 212 MB HBM traffic).
// K-frags read from kT (LDS) inside the loop instead of a bk[8] reg cache.
// ---------------------------------------------------------------------------
__global__ __launch_bounds__(256) void attn_kernel(const unsigned short* __restrict__ qg,
                                                   const unsigned short* __restrict__ kg,
                                                   const unsigned short* __restrict__ vg,
                                                   const unsigned short* __restrict__ peg,
                                                   float* __restrict__ outg)
{
    __shared__ unsigned short qT[512][16];     // qT[w][h]  16 KB
    __shared__ unsigned short kT[512][16];     // kT[v][h]  16 KB
    __shared__ float rcpl[512];                // 1 / l[w]   2 KB
    __shared__ unsigned int Pt[4][16][20];     // per-wave P' tile, 5.12 KB  (39.9 total)

    const int tid = threadIdx.x;
    const int bc = blockIdx.x;                 // 1024 = (b*64 + c)
    const size_t base = (size_t)bc << 13;      // *8192 elems

    const int lane = tid & 63, wv = tid >> 6;

    // ---- stage q,k transposed via in-register v_perm ----
    {
        const int wp = (wv << 7) + (lane << 1);   // wave's w-pair
        unsigned int rq[16], rk[16];
        #pragma unroll
        for (int h = 0; h < 16; ++h) {
            rq[h] = *(const unsigned int*)(qg + base + (h << 9) + wp);
            rk[h] = *(const unsigned int*)(kg + base + (h << 9) + wp);
        }
        unsigned int lo[8], hi[8];
        #pragma unroll
        for (int j = 0; j < 8; ++j) {
            lo[j] = __builtin_amdgcn_perm(rq[2 * j + 1], rq[2 * j], 0x05040100u);
            hi[j] = __builtin_amdgcn_perm(rq[2 * j + 1], rq[2 * j], 0x07060302u);
        }
        *(uint4*)&qT[wp][0]     = make_uint4(lo[0], lo[1], lo[2], lo[3]);
        *(uint4*)&qT[wp][8]     = make_uint4(lo[4], lo[5], lo[6], lo[7]);
        *(uint4*)&qT[wp + 1][0] = make_uint4(hi[0], hi[1], hi[2], hi[3]);
        *(uint4*)&qT[wp + 1][8] = make_uint4(hi[4], hi[5], hi[6], hi[7]);
        #pragma unroll
        for (int j = 0; j < 8; ++j) {
            lo[j] = __builtin_amdgcn_perm(rk[2 * j + 1], rk[2 * j], 0x05040100u);
            hi[j] = __builtin_amdgcn_perm(rk[2 * j + 1], rk[2 * j], 0x07060302u);
        }
        *(uint4*)&kT[wp][0]     = make_uint4(lo[0], lo[1], lo[2], lo[3]);
        *(uint4*)&kT[wp][8]     = make_uint4(lo[4], lo[5], lo[6], lo[7]);
        *(uint4*)&kT[wp + 1][0] = make_uint4(hi[0], hi[1], hi[2], hi[3]);
        *(uint4*)&kT[wp + 1][8] = make_uint4(hi[4], hi[5], hi[6], hi[7]);
    }
    __syncthreads();

    const int n = lane & 15, quad = lane >> 4;
    const short8 z8 = {0, 0, 0, 0, 0, 0, 0, 0};
    const floatx4 zf = {0.f, 0.f, 0.f, 0.f};

    // ---- pass A: softmax denominators ----
    for (int s = 0; s < 8; ++s) {
        const int w0 = (wv * 8 + s) * 16;
        short8 aq = (quad < 2) ? *(const short8*)&qT[w0 + n][quad * 8] : z8;  // k=h pad
        float sum[4] = {0.f, 0.f, 0.f, 0.f};
        for (int vt = 0; vt < 32; ++vt) {
            short8 bk = (quad < 2) ? *(const short8*)&kT[vt * 16 + n][quad * 8] : z8;
            floatx4 d = __builtin_amdgcn_mfma_f32_16x16x32_bf16(aq, bk, zf, 0, 0, 0);
            #pragma unroll
            for (int r = 0; r < 4; ++r) sum[r] += __builtin_amdgcn_exp2f(d[r]);
        }
        #pragma unroll
        for (int off = 1; off < 16; off <<= 1) {
            #pragma unroll
            for (int r = 0; r < 4; ++r) sum[r] += __shfl_xor(sum[r], off, 64);
        }
        if (n == 0) {
            #pragma unroll
            for (int r = 0; r < 4; ++r)
                rcpl[w0 + quad * 4 + r] = 1.0f / fmaxf(sum[r], 1e-30f);
        }
    }
    __syncthreads();

    // ---- pass B: wave owns v-range [wv*128, wv*128+128) ----
    const int v0 = wv * 128;
    floatx4 acc[8];
    #pragma unroll
    for (int nt = 0; nt < 8; ++nt) acc[nt] = zf;

    for (int kc = 0; kc < 16; ++kc) {          // w-chunks of 32 (contraction)
        const int w0 = kc * 32;
        short8 aq0 = (quad < 2) ? *(const short8*)&qT[w0 + n][quad * 8] : z8;
        short8 aq1 = (quad < 2) ? *(const short8*)&qT[w0 + 16 + n][quad * 8] : z8;
        // av' = bf16( V[h=n][w0+quad*8+j] * rcpl[w0+quad*8+j] )  -- per-kc fold
        short8 vraw = *(const short8*)(vg + base + ((size_t)n << 9) + w0 + quad * 8);
        const float4 ra = *(const float4*)&rcpl[w0 + quad * 8];
        const float4 rb = *(const float4*)&rcpl[w0 + quad * 8 + 4];
        short8 av;
        av[0] = (short)f2bf(bf2f((unsigned short)vraw[0]) * ra.x);
        av[1] = (short)f2bf(bf2f((unsigned short)vraw[1]) * ra.y);
        av[2] = (short)f2bf(bf2f((unsigned short)vraw[2]) * ra.z);
        av[3] = (short)f2bf(bf2f((unsigned short)vraw[3]) * ra.w);
        av[4] = (short)f2bf(bf2f((unsigned short)vraw[4]) * rb.x);
        av[5] = (short)f2bf(bf2f((unsigned short)vraw[5]) * rb.y);
        av[6] = (short)f2bf(bf2f((unsigned short)vraw[6]) * rb.z);
        av[7] = (short)f2bf(bf2f((unsigned short)vraw[7]) * rb.w);

        #pragma unroll
        for (int nt = 0; nt < 8; ++nt) {
            // K-frag from LDS (not reg-cached: keeps VGPR < 128, no spill)
            short8 bkv = (quad < 2) ? *(const short8*)&kT[v0 + nt * 16 + n][quad * 8] : z8;
            floatx4 s0 = __builtin_amdgcn_mfma_f32_16x16x32_bf16(aq0, bkv, zf, 0, 0, 0);
            floatx4 s1 = __builtin_amdgcn_mfma_f32_16x16x32_bf16(aq1, bkv, zf, 0, 0, 0);
            // P' = exp2(S'), bf16-packed, via per-wave LDS tile (C->B layout)
            const unsigned int u00 = pkbf(__builtin_amdgcn_exp2f(s0[0]),
                                          __builtin_amdgcn_exp2f(s0[1]));
            const unsigned int u01 = pkbf(__builtin_amdgcn_exp2f(s0[2]),
                                          __builtin_amdgcn_exp2f(s0[3]));
            const unsigned int u10 = pkbf(__builtin_amdgcn_exp2f(s1[0]),
                                          __builtin_amdgcn_exp2f(s1[1]));
            const unsigned int u11 = pkbf(__builtin_amdgcn_exp2f(s1[2]),
                                          __builtin_amdgcn_exp2f(s1[3]));
            Pt[wv][n][quad * 2]         = u00;   // w-local quad*4 + 0..1
            Pt[wv][n][quad * 2 + 1]     = u01;   // w-local quad*4 + 2..3
            Pt[wv][n][8 + quad * 2]     = u10;   // w-local 16+quad*4 + 0..1
            Pt[wv][n][8 + quad * 2 + 1] = u11;   // w-local 16+quad*4 + 2..3
            __asm__ volatile("" ::: "memory");   // no load hoisting past stores
            union { uint4 u; short8 s; } bpc;
            bpc.u = *(const uint4*)&Pt[wv][n][quad * 4];  // B: k=w-local, n=v
            __asm__ volatile("" ::: "memory");
            acc[nt] = __builtin_amdgcn_mfma_f32_16x16x32_bf16(av, bpc.s, acc[nt], 0, 0, 0);
        }
    }

    // ---- epilogue: + pe (bf16 from ws), store fp32 (write-only d_out) ----
    #pragma unroll
    for (int nt = 0; nt < 8; ++nt) {
        #pragma unroll
        for (int r = 0; r < 4; ++r) {
            const int hrow = quad * 4 + r;
            const size_t o = base + ((size_t)hrow << 9) + (v0 + nt * 16 + n);
            outg[o] = acc[nt][r] + bf2f(peg[o]);
        }
    }
}

// ---------------------------------------------------------------------------
extern "C" void kernel_launch(void* const* d_in, const int* in_sizes, int n_in,
                              void* d_out, int out_size, void* d_ws, size_t ws_size,
                              hipStream_t stream)
{
    AllIn ai;
    for (int i = 0; i < 21; ++i) ai.p[i] = d_in[i];

    unsigned short* ws  = (unsigned short*)d_ws;   // q,k,v,pe bf16: exactly 64 MiB
    float* out = (float*)d_out;                    // write-only fp32 output

    conv_kernel<<<512, 256, 0, stream>>>(ai, ws);
    attn_kernel<<<1024, 256, 0, stream>>>(ws,
                                          ws + (size_t)Q_ELEMS,
                                          ws + 2 * (size_t)Q_ELEMS,
                                          ws + 3 * (size_t)Q_ELEMS,
                                          out);
}

// Round 8
// 266.420 us; speedup vs baseline: 1.3354x; 1.3354x over previous
//
#include <hip/hip_runtime.h>
#include <hip/hip_bf16.h>

// ConvAttention: 4x [conv(1,5)+BN+LReLU(0.3)] -> per-(b,c) attention over W with
// softmax over last axis, + pe residual.  B=16 Cin=32 Cout=64 H=16 W=512.
// fp32 in / fp32 out.  Internals bf16 MFMA, fp32 accumulation.
// R8: attn keeps R7's small live set AND re-adds (256,4) bound (R6/R7 A/B
// showed occupancy dominates: 36%+spills=124us beats 11.5% clean=204us).
// conv: 1024 blocks (b,h,w-quarter 128) + contiguous float4 weight loads
// (40 floats/lane) instead of 160 scalar stride-5 loads; (256,4).

typedef __attribute__((ext_vector_type(8))) short short8;   // 8 x bf16 (4 VGPR)
typedef __attribute__((ext_vector_type(4))) float floatx4;  // MFMA acc

#define Q_ELEMS 8388608u     // 16*64*16*512 elements per tensor (q/k/v/pe)
#define LOG2E   1.44269504088896340736f

__device__ __forceinline__ float bf2f(unsigned short u) {
    union { unsigned int i; float f; } c; c.i = ((unsigned int)u) << 16; return c.f;
}
__device__ __forceinline__ unsigned short f2bf(float f) {   // RNE
    union { unsigned int i; float f; } c; c.f = f;
    unsigned int r = c.i + 0x7FFFu + ((c.i >> 16) & 1u);
    return (unsigned short)(r >> 16);
}
__device__ __forceinline__ unsigned int pkbf(float lo, float hi) {  // bf16(hi)<<16|bf16(lo)
    __hip_bfloat162 h2 = __float22bfloat162_rn(make_float2(lo, hi));
    union { __hip_bfloat162 h; unsigned int u; } c; c.h = h2; return c.u;
}

struct AllIn { const void* p[21]; };

// ---------------------------------------------------------------------------
// Conv kernel: one block per (b, h, w-quarter). Stages x[b,:,h,wq*128±2] once,
// runs all 4 sel GEMMs.  im2col GEMM, M=co(64) N=w(128) K=160, k = t*32+ci.
// Per-lane weight fragment = 40 CONTIGUOUS floats -> 10 float4 loads.
// Epilogue via per-wave LDS tile -> coalesced uint4 bf16 stores to ws.
// sel==0 (q) pre-scaled by log2(e) (LReLU commutes with positive scale).
// ---------------------------------------------------------------------------
__global__ __launch_bounds__(256, 4) void conv_kernel(AllIn in,
                                                      unsigned short* __restrict__ ws_out)
{
    __shared__ unsigned short xt[132][40];    // xt[wl+2][ci]; rows 80B, 10.6 KB
    __shared__ unsigned short Dt[4][16][40];  // per-wave C tile, 5.1 KB (15.7 total)

    const bool isbf = (*(const unsigned int*)in.p[5] == 0x3F803F80u);

    const int tid = threadIdx.x;
    const int blk = blockIdx.x;               // 1024 = 16b * 16h * 4wq
    const int wq = blk & 3, h = (blk >> 2) & 15, b = blk >> 6;
    const int w0g = wq * 128;

    // ---- stage x[b,:,h, w0g-2 .. w0g+129] transposed into LDS (bf16) ----
    {
        const int lw = tid & 63;              // stride-1 lane mapping
        const int cg = tid >> 6;              // ci group 0..3
        for (int it = 0; it < 8; ++it) {
            const int ci = it * 4 + cg;
            const size_t row = ((size_t)(b * 32 + ci) * 16 + h) << 9;
            #pragma unroll
            for (int m = 0; m < 2; ++m) {
                const int w = lw + 64 * m;    // 0..127
                unsigned short e = isbf ? ((const unsigned short*)in.p[0])[row + w0g + w]
                                        : f2bf(((const float*)in.p[0])[row + w0g + w]);
                xt[w + 2][ci] = e;
            }
        }
    }
    if (tid < 128) {                          // halo rows 0,1 and 130,131
        const int ci = tid >> 2, p = tid & 3;
        const int r  = (p < 2) ? p : 128 + p;
        const int gw = w0g + r - 2;
        unsigned short val = 0;
        if (gw >= 0 && gw < 512) {
            const size_t row = ((size_t)(b * 32 + ci) * 16 + h) << 9;
            val = isbf ? ((const unsigned short*)in.p[0])[row + gw]
                       : f2bf(((const float*)in.p[0])[row + gw]);
        }
        xt[r][ci] = val;
    }
    __syncthreads();

    const int lane = tid & 63, wv = tid >> 6;
    const int n = lane & 15, quad = lane >> 4;
    const int co0 = wv * 16;                  // wave's M-tile

    for (int sel = 0; sel < 4; ++sel) {
        // ---- A frags: w[co0+n][quad*8+j][kk] = 40 contiguous elems ----
        short8 afrag[5];
        if (isbf) {
            const unsigned short* wb = (const unsigned short*)in.p[1 + 5 * sel]
                                       + (co0 + n) * 160 + quad * 40;
            #pragma unroll
            for (int p = 0; p < 5; ++p) {
                const uint4 d = *(const uint4*)(wb + p * 8);
                const unsigned short* e = (const unsigned short*)&d;
                #pragma unroll
                for (int t = 0; t < 8; ++t) {
                    const int idx = p * 8 + t;        // = j*5 + kk
                    afrag[idx % 5][idx / 5] = (short)e[t];
                }
            }
        } else {
            const float* wb = (const float*)in.p[1 + 5 * sel]
                              + (co0 + n) * 160 + quad * 40;
            #pragma unroll
            for (int p = 0; p < 10; ++p) {
                const float4 f = *(const float4*)(wb + p * 4);
                const float* e = (const float*)&f;
                #pragma unroll
                for (int t = 0; t < 4; ++t) {
                    const int idx = p * 4 + t;        // = j*5 + kk
                    afrag[idx % 5][idx / 5] = (short)f2bf(e[t]);
                }
            }
        }
        // ---- BN constants (D rows = quad*4+r); q gets the log2e fold ----
        float sc[4], sh[4];
        #pragma unroll
        for (int r = 0; r < 4; ++r) {
            const int co = co0 + quad * 4 + r;
            const void* gp = in.p[2 + 5 * sel];
            const void* bp = in.p[3 + 5 * sel];
            const void* mp = in.p[4 + 5 * sel];
            const void* vp = in.p[5 + 5 * sel];
            float gg = isbf ? bf2f(((const unsigned short*)gp)[co]) : ((const float*)gp)[co];
            float bb = isbf ? bf2f(((const unsigned short*)bp)[co]) : ((const float*)bp)[co];
            float mm = isbf ? bf2f(((const unsigned short*)mp)[co]) : ((const float*)mp)[co];
            float vv = isbf ? bf2f(((const unsigned short*)vp)[co]) : ((const float*)vp)[co];
            sc[r] = gg * rsqrtf(vv + 1e-5f);
            sh[r] = bb - mm * sc[r];
            if (sel == 0) { sc[r] *= LOG2E; sh[r] *= LOG2E; }
        }

        unsigned short* outq = ws_out + (size_t)sel * Q_ELEMS;
        for (int g = 0; g < 4; ++g) {         // 32-w groups within this quarter
            const int w0l = g * 32;
            #pragma unroll
            for (int half = 0; half < 2; ++half) {
                const int w0 = w0l + half * 16;
                floatx4 acc = {0.f, 0.f, 0.f, 0.f};
                #pragma unroll
                for (int kk = 0; kk < 5; ++kk) {
                    short8 bfrag = *(const short8*)&xt[w0 + n + kk][quad * 8];
                    acc = __builtin_amdgcn_mfma_f32_16x16x32_bf16(afrag[kk], bfrag, acc, 0, 0, 0);
                }
                #pragma unroll
                for (int r = 0; r < 4; ++r) {
                    float y = acc[r] * sc[r] + sh[r];
                    y = fmaxf(y, 0.3f * y);                   // LeakyReLU(0.3)
                    Dt[wv][quad * 4 + r][half * 16 + n] = f2bf(y);
                }
            }
            __asm__ volatile("" ::: "memory");
            const uint4 d = *(const uint4*)&Dt[wv][n][quad * 8];
            __asm__ volatile("" ::: "memory");
            *(uint4*)&outq[(((size_t)(b * 64 + co0 + n) * 16 + h) << 9)
                           + w0g + w0l + quad * 8] = d;
        }
    }
}

// ---------------------------------------------------------------------------
// Attention kernel: one block (4 waves) per (b,c) pair, 4 blocks/CU target.
//   pass A: l[w] = sum_v exp2(S'[w,v]); S' = Q'^T K (q pre-scaled by log2e)
//   pass B: out[h,v] = sum_w (V[h,w]/l[w]) * exp2(S'[w,v])  + pe[h,v]
// (256,4): R6/R7 A/B showed 4 blocks/CU (even with some spill) >> 3 blocks/CU.
// Small live set (no bk cache; K-frags re-read from LDS) minimizes the spill.
// ---------------------------------------------------------------------------
__global__ __launch_bounds__(256, 4) void attn_kernel(const unsigned short* __restrict__ qg,
                                                      const unsigned short* __restrict__ kg,
                                                      const unsigned short* __restrict__ vg,
                                                      const unsigned short* __restrict__ peg,
                                                      float* __restrict__ outg)
{
    __shared__ unsigned short qT[512][16];     // qT[w][h]  16 KB
    __shared__ unsigned short kT[512][16];     // kT[v][h]  16 KB
    __shared__ float rcpl[512];                // 1 / l[w]   2 KB
    __shared__ unsigned int Pt[4][16][20];     // per-wave P' tile, 5.12 KB  (39.9 total)

    const int tid = threadIdx.x;
    const int bc = blockIdx.x;                 // 1024 = (b*64 + c)
    const size_t base = (size_t)bc << 13;      // *8192 elems

    const int lane = tid & 63, wv = tid >> 6;

    // ---- stage q,k transposed via in-register v_perm ----
    {
        const int wp = (wv << 7) + (lane << 1);   // wave's w-pair
        unsigned int rq[16], rk[16];
        #pragma unroll
        for (int h = 0; h < 16; ++h) {
            rq[h] = *(const unsigned int*)(qg + base + (h << 9) + wp);
            rk[h] = *(const unsigned int*)(kg + base + (h << 9) + wp);
        }
        unsigned int lo[8], hi[8];
        #pragma unroll
        for (int j = 0; j < 8; ++j) {
            lo[j] = __builtin_amdgcn_perm(rq[2 * j + 1], rq[2 * j], 0x05040100u);
            hi[j] = __builtin_amdgcn_perm(rq[2 * j + 1], rq[2 * j], 0x07060302u);
        }
        *(uint4*)&qT[wp][0]     = make_uint4(lo[0], lo[1], lo[2], lo[3]);
        *(uint4*)&qT[wp][8]     = make_uint4(lo[4], lo[5], lo[6], lo[7]);
        *(uint4*)&qT[wp + 1][0] = make_uint4(hi[0], hi[1], hi[2], hi[3]);
        *(uint4*)&qT[wp + 1][8] = make_uint4(hi[4], hi[5], hi[6], hi[7]);
        #pragma unroll
        for (int j = 0; j < 8; ++j) {
            lo[j] = __builtin_amdgcn_perm(rk[2 * j + 1], rk[2 * j], 0x05040100u);
            hi[j] = __builtin_amdgcn_perm(rk[2 * j + 1], rk[2 * j], 0x07060302u);
        }
        *(uint4*)&kT[wp][0]     = make_uint4(lo[0], lo[1], lo[2], lo[3]);
        *(uint4*)&kT[wp][8]     = make_uint4(lo[4], lo[5], lo[6], lo[7]);
        *(uint4*)&kT[wp + 1][0] = make_uint4(hi[0], hi[1], hi[2], hi[3]);
        *(uint4*)&kT[wp + 1][8] = make_uint4(hi[4], hi[5], hi[6], hi[7]);
    }
    __syncthreads();

    const int n = lane & 15, quad = lane >> 4;
    const short8 z8 = {0, 0, 0, 0, 0, 0, 0, 0};
    const floatx4 zf = {0.f, 0.f, 0.f, 0.f};

    // ---- pass A: softmax denominators ----
    for (int s = 0; s < 8; ++s) {
        const int w0 = (wv * 8 + s) * 16;
        short8 aq = (quad < 2) ? *(const short8*)&qT[w0 + n][quad * 8] : z8;  // k=h pad
        float sum[4] = {0.f, 0.f, 0.f, 0.f};
        for (int vt = 0; vt < 32; ++vt) {
            short8 bk = (quad < 2) ? *(const short8*)&kT[vt * 16 + n][quad * 8] : z8;
            floatx4 d = __builtin_amdgcn_mfma_f32_16x16x32_bf16(aq, bk, zf, 0, 0, 0);
            #pragma unroll
            for (int r = 0; r < 4; ++r) sum[r] += __builtin_amdgcn_exp2f(d[r]);
        }
        #pragma unroll
        for (int off = 1; off < 16; off <<= 1) {
            #pragma unroll
            for (int r = 0; r < 4; ++r) sum[r] += __shfl_xor(sum[r], off, 64);
        }
        if (n == 0) {
            #pragma unroll
            for (int r = 0; r < 4; ++r)
                rcpl[w0 + quad * 4 + r] = 1.0f / fmaxf(sum[r], 1e-30f);
        }
    }
    __syncthreads();

    // ---- pass B: wave owns v-range [wv*128, wv*128+128) ----
    const int v0 = wv * 128;
    floatx4 acc[8];
    #pragma unroll
    for (int nt = 0; nt < 8; ++nt) acc[nt] = zf;

    for (int kc = 0; kc < 16; ++kc) {          // w-chunks of 32 (contraction)
        const int w0 = kc * 32;
        short8 aq0 = (quad < 2) ? *(const short8*)&qT[w0 + n][quad * 8] : z8;
        short8 aq1 = (quad < 2) ? *(const short8*)&qT[w0 + 16 + n][quad * 8] : z8;
        // av' = bf16( V[h=n][w0+quad*8+j] * rcpl[w0+quad*8+j] )  -- per-kc fold
        short8 vraw = *(const short8*)(vg + base + ((size_t)n << 9) + w0 + quad * 8);
        const float4 ra = *(const float4*)&rcpl[w0 + quad * 8];
        const float4 rb = *(const float4*)&rcpl[w0 + quad * 8 + 4];
        short8 av;
        av[0] = (short)f2bf(bf2f((unsigned short)vraw[0]) * ra.x);
        av[1] = (short)f2bf(bf2f((unsigned short)vraw[1]) * ra.y);
        av[2] = (short)f2bf(bf2f((unsigned short)vraw[2]) * ra.z);
        av[3] = (short)f2bf(bf2f((unsigned short)vraw[3]) * ra.w);
        av[4] = (short)f2bf(bf2f((unsigned short)vraw[4]) * rb.x);
        av[5] = (short)f2bf(bf2f((unsigned short)vraw[5]) * rb.y);
        av[6] = (short)f2bf(bf2f((unsigned short)vraw[6]) * rb.z);
        av[7] = (short)f2bf(bf2f((unsigned short)vraw[7]) * rb.w);

        #pragma unroll
        for (int nt = 0; nt < 8; ++nt) {
            // K-frag from LDS (not reg-cached: keeps arch-VGPR small)
            short8 bkv = (quad < 2) ? *(const short8*)&kT[v0 + nt * 16 + n][quad * 8] : z8;
            floatx4 s0 = __builtin_amdgcn_mfma_f32_16x16x32_bf16(aq0, bkv, zf, 0, 0, 0);
            floatx4 s1 = __builtin_amdgcn_mfma_f32_16x16x32_bf16(aq1, bkv, zf, 0, 0, 0);
            // P' = exp2(S'), bf16-packed, via per-wave LDS tile (C->B layout)
            const unsigned int u00 = pkbf(__builtin_amdgcn_exp2f(s0[0]),
                                          __builtin_amdgcn_exp2f(s0[1]));
            const unsigned int u01 = pkbf(__builtin_amdgcn_exp2f(s0[2]),
                                          __builtin_amdgcn_exp2f(s0[3]));
            const unsigned int u10 = pkbf(__builtin_amdgcn_exp2f(s1[0]),
                                          __builtin_amdgcn_exp2f(s1[1]));
            const unsigned int u11 = pkbf(__builtin_amdgcn_exp2f(s1[2]),
                                          __builtin_amdgcn_exp2f(s1[3]));
            Pt[wv][n][quad * 2]         = u00;   // w-local quad*4 + 0..1
            Pt[wv][n][quad * 2 + 1]     = u01;   // w-local quad*4 + 2..3
            Pt[wv][n][8 + quad * 2]     = u10;   // w-local 16+quad*4 + 0..1
            Pt[wv][n][8 + quad * 2 + 1] = u11;   // w-local 16+quad*4 + 2..3
            __asm__ volatile("" ::: "memory");   // no load hoisting past stores
            union { uint4 u; short8 s; } bpc;
            bpc.u = *(const uint4*)&Pt[wv][n][quad * 4];  // B: k=w-local, n=v
            __asm__ volatile("" ::: "memory");
            acc[nt] = __builtin_amdgcn_mfma_f32_16x16x32_bf16(av, bpc.s, acc[nt], 0, 0, 0);
        }
    }

    // ---- epilogue: + pe (bf16 from ws), store fp32 (write-only d_out) ----
    #pragma unroll
    for (int nt = 0; nt < 8; ++nt) {
        #pragma unroll
        for (int r = 0; r < 4; ++r) {
            const int hrow = quad * 4 + r;
            const size_t o = base + ((size_t)hrow << 9) + (v0 + nt * 16 + n);
            outg[o] = acc[nt][r] + bf2f(peg[o]);
        }
    }
}

// ---------------------------------------------------------------------------
extern "C" void kernel_launch(void* const* d_in, const int* in_sizes, int n_in,
                              void* d_out, int out_size, void* d_ws, size_t ws_size,
                              hipStream_t stream)
{
    AllIn ai;
    for (int i = 0; i < 21; ++i) ai.p[i] = d_in[i];

    unsigned short* ws  = (unsigned short*)d_ws;   // q,k,v,pe bf16: exactly 64 MiB
    float* out = (float*)d_out;                    // write-only fp32 output

    conv_kernel<<<1024, 256, 0, stream>>>(ai, ws);
    attn_kernel<<<1024, 256, 0, stream>>>(ws,
                                          ws + (size_t)Q_ELEMS,
                                          ws + 2 * (size_t)Q_ELEMS,
                                          ws + 3 * (size_t)Q_ELEMS,
                                          out);
}